// Round 10
// baseline (52.867 us; speedup 1.0000x reference)
//
#include <hip/hip_runtime.h>
#include <hip/hip_bf16.h>
#include <stdint.h>

// Problem constants
#define B_ROWS 16384
#define F_DIM  512
#define K_OUT  1000
#define K_PAD  1024

// GEMM tile: 128x128, BK=32, 4 waves. LDS ~48.5KB -> 3 blocks/CU resident.
#define BM 128
#define BN 128
#define BK 32

typedef __attribute__((ext_vector_type(4))) float f32x4;
typedef __attribute__((ext_vector_type(8))) short short8;
typedef unsigned short u16;
typedef unsigned int   u32;

// Workspace layout (bytes)
#define OFF_WB   0                 // 1024*512*2 = 1048576
#define OFF_WSQ  1048576           // 1024*4     = 4096

// LDS layout (bytes)
#define A0_OFF   0                 // fp32 A tile [128][32] = 16KB
#define A1_OFF   16384
#define B0_OFF   32768             // bf16 B tile [128][32] = 8KB
#define B1_OFF   40960
#define DSQ_OFF  49152             // float[128]
#define LDS_SZ   49664             // 3 blocks/CU: 148992 <= 163840

__device__ __forceinline__ u16 f2bf(float f) {
  union { float f; u32 u; } v; v.f = f;
  u32 u = v.u;
  u32 r = (u + 0x7fffu + ((u >> 16) & 1u)) >> 16;   // RNE
  return (u16)r;
}

// packed f32x2 -> bf16x2 (RNE), D[15:0]=bf16(lo), D[31:16]=bf16(hi)
__device__ __forceinline__ u32 pkbf(float lo, float hi) {
  u32 d;
  asm("v_cvt_pk_bf16_f32 %0, %1, %2" : "=v"(d) : "v"(lo), "v"(hi));
  return d;
}

// ---- prep: cast W -> bf16 padded to K_PAD rows, row sums of squares ----
__global__ void prep_W(const float* __restrict__ W, u16* __restrict__ Wb,
                       float* __restrict__ wsq) {
  int w    = threadIdx.x >> 6;
  int lane = threadIdx.x & 63;
  int row  = blockIdx.x * 4 + w;
  uint4 p; p.x = p.y = p.z = p.w = 0u;
  float s = 0.f;
  if (row < K_OUT) {
    const float* src = W + (size_t)row * F_DIM + lane * 8;
    float4 v0 = *(const float4*)src;
    float4 v1 = *(const float4*)(src + 4);
    s = v0.x*v0.x + v0.y*v0.y + v0.z*v0.z + v0.w*v0.w
      + v1.x*v1.x + v1.y*v1.y + v1.z*v1.z + v1.w*v1.w;
    p.x = (u32)f2bf(v0.x) | ((u32)f2bf(v0.y) << 16);
    p.y = (u32)f2bf(v0.z) | ((u32)f2bf(v0.w) << 16);
    p.z = (u32)f2bf(v1.x) | ((u32)f2bf(v1.y) << 16);
    p.w = (u32)f2bf(v1.z) | ((u32)f2bf(v1.w) << 16);
  }
#pragma unroll
  for (int off = 32; off >= 1; off >>= 1) s += __shfl_xor(s, off);
  if (lane == 0) wsq[row] = s;
  *(uint4*)(Wb + (size_t)row * F_DIM + lane * 8) = p;
}

// ---- async global -> LDS, 16B per lane (dest is wave-uniform base + lane*16) ----
__device__ __forceinline__ void gload_lds16(const void* g, void* l) {
  __builtin_amdgcn_global_load_lds(
      (const __attribute__((address_space(1))) void*)g,
      (__attribute__((address_space(3))) void*)l,
      16, 0, 0);
}

// ---- fused GEMM: A staged as RAW FP32 via gload_lds (no prep_D!), cvt on the
// frag-read side; B staged bf16 from Wb; dsq accumulated in-kernel.
// out[m][n] = gamma[n] * (2*cross[m][n] - dsq[m] - wsq[n]), n < K_OUT
//
// A tile: fp32 [128 rows][32 k] = 16KB; row = 128B = 8 slots of 16B; slot s of
// row r stored at (s ^ (r&7)) via pre-swizzled global SOURCE (rule #21).
// B tile: bf16 [128 rows][32 k] = 8KB; row = 64B = 4 slots; XOR (r&3).
//
// Per K-tile (2 barriers, counted vmcnt(6), no vmcnt(0) in loop):
//   issue 6 gload_lds for tile t+1 (4 A fp32 + 2 B bf16) into buf^1
//   s_waitcnt vmcnt(6) -> tile t's 6 loads landed; s_barrier
//   per mi: 2x ds_read float4 (A fp32) -> 4x v_cvt_pk_bf16_f32 -> a-frag;
//           dsq fma on wn==0 waves; 1x ds_read_b128 -> b-frag
//   setprio(1); 16 MFMA; setprio(0); s_barrier
// t=15 issues phantom tile-16 loads (k wraps to 0) for ledger uniformity.

#define STAGE_A(g)                                                             \
  {                                                                            \
    int r  = (g) * 32 + w * 8 + ra8;                                           \
    int sc = s8 ^ (r & 7);                                                     \
    gload_lds16(Dg + (size_t)r * F_DIM + kbn + sc * 4,                         \
                sAn + (g) * 4096 + w * 1024);                                  \
  }

#define STAGE_B(j)                                                             \
  {                                                                            \
    int r  = (j) * 64 + w * 16 + rb4;                                          \
    int sc = s4 ^ (r & 3);                                                     \
    gload_lds16(Bg + (size_t)r * F_DIM + kbn + sc * 8,                         \
                sBn + (j) * 4096 + w * 1024);                                  \
  }

__global__ __launch_bounds__(256, 3) void gemm_eps(
    const float* __restrict__ D,     // [B_ROWS][F_DIM] fp32
    const u16*   __restrict__ Bw,    // [K_PAD][F_DIM]  bf16 (padded rows 0)
    const float* __restrict__ wsq,   // [K_PAD]
    const float* __restrict__ gamma, // [K_OUT]
    float* __restrict__ out) {       // [B_ROWS][K_OUT]
  __shared__ __align__(16) char lds[LDS_SZ];
  float* dsq_s = (float*)(lds + DSQ_OFF);   // [128]

  const int tid  = threadIdx.x;
  const int w    = tid >> 6;     // wave 0..3
  const int lane = tid & 63;
  const int lr   = lane & 15;
  const int lk4  = lane >> 4;
  const int wm   = w >> 1;       // 2 M-waves
  const int wn   = w & 1;        // 2 N-waves
  const int ra8  = lane >> 3;    // A staging: row-within-8
  const int s8   = lane & 7;     //            16B slot (8/row)
  const int rb4  = lane >> 2;    // B staging: row-within-16
  const int s4   = lane & 3;     //            16B slot (4/row)

  // XCD-aware swizzle (grid=1024, %8==0 -> bijective). The 8 N-tile blocks of
  // one A-panel are consecutive wg on one XCD -> fp32 D fetched from HBM once.
  const int bid = blockIdx.x;
  const int wg  = (bid & 7) * 128 + (bid >> 3);
  const int mt  = wg >> 3;       // 128 M-tiles
  const int nt  = wg & 7;        // 8 N-tiles
  const int m0  = mt * BM;
  const int n0  = nt * BN;

  const float* Dg = D  + (size_t)m0 * F_DIM;
  const u16*   Bg = Bw + (size_t)n0 * F_DIM;

  f32x4 acc[4][4];
#pragma unroll
  for (int i = 0; i < 4; ++i)
#pragma unroll
    for (int j = 0; j < 4; ++j) acc[i][j] = (f32x4){0.f, 0.f, 0.f, 0.f};
  float pa[4] = {0.f, 0.f, 0.f, 0.f};

  // prologue: stage K-tile 0 into buf0 (6 loads/thread, left in flight)
  {
    char* sAn = lds + A0_OFF;
    char* sBn = lds + B0_OFF;
    const int kbn = 0;
    STAGE_A(0) STAGE_A(1) STAGE_A(2) STAGE_A(3)
    STAGE_B(0) STAGE_B(1)
  }

#pragma unroll 2
  for (int t = 0; t < 16; ++t) {
    const char* sAc = lds + ((t & 1) ? A1_OFF : A0_OFF);
    const char* sBc = lds + ((t & 1) ? B1_OFF : B0_OFF);
    char* sAn = lds + ((t & 1) ? A0_OFF : A1_OFF);
    char* sBn = lds + ((t & 1) ? B0_OFF : B1_OFF);
    const int kbn = ((t + 1) & 15) * BK;  // t=15 phantom wraps to k=0: harmless

    // issue next tile's 6 loads (in flight across this tile's compute)
    STAGE_A(0) STAGE_A(1) STAGE_A(2) STAGE_A(3)
    STAGE_B(0) STAGE_B(1)

    asm volatile("s_waitcnt vmcnt(6)" ::: "memory");  // tile t resident
    __builtin_amdgcn_s_barrier();
    asm volatile("" ::: "memory");

    short8 a[4], b[4];
#pragma unroll
    for (int mi = 0; mi < 4; ++mi) {
      int rA = wm * 64 + mi * 16 + lr;
      const char* baseA = sAc + rA * 128;
      float4 f0 = *(const float4*)(baseA + ((((lk4 << 1) | 0) ^ (rA & 7)) << 4));
      float4 f1 = *(const float4*)(baseA + ((((lk4 << 1) | 1) ^ (rA & 7)) << 4));
      union { uint4 u; short8 s; } cv;
      cv.u.x = pkbf(f0.x, f0.y); cv.u.y = pkbf(f0.z, f0.w);
      cv.u.z = pkbf(f1.x, f1.y); cv.u.w = pkbf(f1.z, f1.w);
      a[mi] = cv.s;
      if (wn == 0)   // each A element touched by exactly one wn==0 lane/block
        pa[mi] += f0.x*f0.x + f0.y*f0.y + f0.z*f0.z + f0.w*f0.w
                + f1.x*f1.x + f1.y*f1.y + f1.z*f1.z + f1.w*f1.w;
      int rB = wn * 64 + mi * 16 + lr;
      b[mi] = *(const short8*)(sBc + rB * 64 + ((lk4 ^ (rB & 3)) << 4));
    }

    __builtin_amdgcn_s_setprio(1);
#pragma unroll
    for (int mi = 0; mi < 4; ++mi)
#pragma unroll
      for (int ni = 0; ni < 4; ++ni)
        acc[mi][ni] = __builtin_amdgcn_mfma_f32_16x16x32_bf16(
            a[mi], b[ni], acc[mi][ni], 0, 0, 0);
    __builtin_amdgcn_s_setprio(0);

    asm volatile("" ::: "memory");
    __builtin_amdgcn_s_barrier();   // buf reads done before t+1 overwrites
  }

  // ---- dsq: reduce partials over the 4 lk4 lanes (wn==0 waves only) ----
  if (wn == 0) {
#pragma unroll
    for (int mi = 0; mi < 4; ++mi) {
      float s = pa[mi];
      s += __shfl_xor(s, 16);
      s += __shfl_xor(s, 32);
      if (lk4 == 0) dsq_s[wm * 64 + mi * 16 + lr] = s;
    }
  }
  __syncthreads();   // drains phantom gloads (vmcnt 0) + dsq_s visible

  // epilogue col-operands
  float g_[4], wq_[4];
#pragma unroll
  for (int ni = 0; ni < 4; ++ni) {
    int col = n0 + wn * 64 + ni * 16 + lr;
    g_[ni]  = (col < K_OUT) ? gamma[col] : 0.f;
    wq_[ni] = wsq[col];
  }
  float4 dl[4];
#pragma unroll
  for (int mi = 0; mi < 4; ++mi)
    dl[mi] = *(const float4*)&dsq_s[wm * 64 + mi * 16 + lk4 * 4];

  // ---- fused epilogue via LDS transpose (coalesced 128B row stores) ----
  float* ch = (float*)lds;       // chunk [64][132] f32 (33792B, below DSQ_OFF)
  const int rl = tid >> 3;
  const int cb = (tid & 7) << 2;
#pragma unroll
  for (int c = 0; c < 2; ++c) {
    __syncthreads();   // previous chunk fully read (c=0: after dsq_s reads)
    if (wm == c) {
#pragma unroll
      for (int mi = 0; mi < 4; ++mi) {
        const int row_l = mi * 16 + lk4 * 4;
#pragma unroll
        for (int j = 0; j < 4; ++j) {
          float dq = (j == 0) ? dl[mi].x : (j == 1) ? dl[mi].y
                   : (j == 2) ? dl[mi].z : dl[mi].w;
#pragma unroll
          for (int ni = 0; ni < 4; ++ni) {
            ch[(row_l + j) * 132 + wn * 64 + ni * 16 + lr] =
                g_[ni] * (2.f * acc[mi][ni][j] - dq - wq_[ni]);
          }
        }
      }
    }
    __syncthreads();   // chunk visible to all waves
#pragma unroll
    for (int half = 0; half < 2; ++half) {
#pragma unroll
      for (int s = 0; s < 4; ++s) {
        int row = half * 32 + rl;
        int col = cb + s * 32;
        if (n0 + col < K_OUT) {
          float4 v = *(const float4*)&ch[row * 132 + col];
          *(float4*)&out[(size_t)(m0 + c * 64 + row) * K_OUT + n0 + col] = v;
        }
      }
    }
  }
}

extern "C" void kernel_launch(void* const* d_in, const int* in_sizes, int n_in,
                              void* d_out, int out_size, void* d_ws, size_t ws_size,
                              hipStream_t stream) {
  const float* D     = (const float*)d_in[0];
  const float* W     = (const float*)d_in[1];
  const float* gamma = (const float*)d_in[2];
  float* out = (float*)d_out;
  char*  ws  = (char*)d_ws;

  u16*   Wb  = (u16*)(ws + OFF_WB);
  float* wsq = (float*)(ws + OFF_WSQ);

  prep_W<<<K_PAD / 4, 256, 0, stream>>>(W, Wb, wsq);

  // grid = (16384/128) * (1024/128) = 1024 blocks, 3 resident/CU
  gemm_eps<<<(B_ROWS / BM) * (K_PAD / BN), 256, 0, stream>>>(
      D, Wb, wsq, gamma, out);
}

// Round 11
// 42.185 us; speedup vs baseline: 1.2532x; 1.2532x over previous
//
#include <hip/hip_runtime.h>
#include <hip/hip_bf16.h>
#include <stdint.h>

// Problem constants
#define B_ROWS 16384
#define F_DIM  512
#define K_OUT  1000
#define K_PAD  1024

// GEMM tile: 128x64, BK=64, 4 waves, 48KB LDS -> 3 blocks/CU resident.
#define BM 128
#define BN 64
#define BK 64

typedef __attribute__((ext_vector_type(4))) float f32x4;
typedef __attribute__((ext_vector_type(8))) short short8;
typedef unsigned short u16;
typedef unsigned int   u32;

// Workspace layout (bytes)
#define OFF_DB   0                               // 16384*512*2 = 16777216
#define OFF_WB   16777216                        // 1024*512*2  = 1048576
#define OFF_DSQ  (16777216 + 1048576)            // 16384*4     = 65536
#define OFF_WSQ  (16777216 + 1048576 + 65536)    // 1024*4      = 4096

// LDS layout (bytes): A dbuf 2x16KB, B dbuf 2x8KB
#define A0_OFF   0
#define A1_OFF   16384
#define B0_OFF   32768
#define B1_OFF   40960
#define LDS_SZ   49152     // 3 blocks/CU (3*48KB = 144KB <= 160KB)

__device__ __forceinline__ u16 f2bf(float f) {
  union { float f; u32 u; } v; v.f = f;
  u32 u = v.u;
  u32 r = (u + 0x7fffu + ((u >> 16) & 1u)) >> 16;   // RNE
  return (u16)r;
}

// ---- merged prep: cast D,W -> bf16 (+pad W), row sums of squares ----
__global__ void prep(const float* __restrict__ D, const float* __restrict__ W,
                     u16* __restrict__ Db, u16* __restrict__ Wb,
                     float* __restrict__ dsq, float* __restrict__ wsq) {
  int w    = threadIdx.x >> 6;
  int lane = threadIdx.x & 63;
  if (blockIdx.x < B_ROWS / 4) {
    int row = blockIdx.x * 4 + w;
    const float* src = D + (size_t)row * F_DIM + lane * 8;
    float4 v0 = *(const float4*)src;
    float4 v1 = *(const float4*)(src + 4);
    float s = v0.x*v0.x + v0.y*v0.y + v0.z*v0.z + v0.w*v0.w
            + v1.x*v1.x + v1.y*v1.y + v1.z*v1.z + v1.w*v1.w;
#pragma unroll
    for (int off = 32; off >= 1; off >>= 1) s += __shfl_xor(s, off);
    if (lane == 0) dsq[row] = s;
    uint4 p;
    p.x = (u32)f2bf(v0.x) | ((u32)f2bf(v0.y) << 16);
    p.y = (u32)f2bf(v0.z) | ((u32)f2bf(v0.w) << 16);
    p.z = (u32)f2bf(v1.x) | ((u32)f2bf(v1.y) << 16);
    p.w = (u32)f2bf(v1.z) | ((u32)f2bf(v1.w) << 16);
    *(uint4*)(Db + (size_t)row * F_DIM + lane * 8) = p;
  } else {
    int row = (blockIdx.x - B_ROWS / 4) * 4 + w;
    uint4 p; p.x = p.y = p.z = p.w = 0u;
    float s = 0.f;
    if (row < K_OUT) {
      const float* src = W + (size_t)row * F_DIM + lane * 8;
      float4 v0 = *(const float4*)src;
      float4 v1 = *(const float4*)(src + 4);
      s = v0.x*v0.x + v0.y*v0.y + v0.z*v0.z + v0.w*v0.w
        + v1.x*v1.x + v1.y*v1.y + v1.z*v1.z + v1.w*v1.w;
      p.x = (u32)f2bf(v0.x) | ((u32)f2bf(v0.y) << 16);
      p.y = (u32)f2bf(v0.z) | ((u32)f2bf(v0.w) << 16);
      p.z = (u32)f2bf(v1.x) | ((u32)f2bf(v1.y) << 16);
      p.w = (u32)f2bf(v1.z) | ((u32)f2bf(v1.w) << 16);
    }
#pragma unroll
    for (int off = 32; off >= 1; off >>= 1) s += __shfl_xor(s, off);
    if (lane == 0) wsq[row] = s;
    *(uint4*)(Wb + (size_t)row * F_DIM + lane * 8) = p;
  }
}

// ---- async global -> LDS, 16B per lane (dest is wave-uniform base + lane*16) ----
__device__ __forceinline__ void gload_lds16(const void* g, void* l) {
  __builtin_amdgcn_global_load_lds(
      (const __attribute__((address_space(1))) void*)g,
      (__attribute__((address_space(3))) void*)l,
      16, 0, 0);
}

// ---- main GEMM + fused epilogue: 128x64 tile, 4 waves, 3 blocks/CU ----
// out[m][n] = gamma[n] * (2*cross[m][n] - dsq[m] - wsq[n]), n < K_OUT
//
// Same per-tile schedule as R7 (the 39.7us anchor): 2 barriers/tile, counted
// vmcnt, 8-slot XOR swizzle; only the tile is 128x64 so 3 blocks fit per CU.
// The hypothesis: cross-BLOCK TLP (3 barrier-independent blocks, 3 waves/SIMD)
// hides barrier skew + L2 latency + store drains that intra-block scheduling
// could not (R2-R8 all null at <=2 blocks/CU).
//
// A tile [128 rows][64 k] bf16 = 16KB; B tile [64 rows][64 k] = 8KB.
// Row = 128B = 8 slots of 16B; k-slot s of row r stored at (s ^ (r&7)) via
// pre-swizzled global source (rule #21). Frag reads use the same XOR.
//
// Per K-tile: issue 6 gload_lds (4 A + 2 B) for t+1; vmcnt(6) -> tile t
// resident; barrier; 12 ds_read_b128; setprio(1); 16 MFMA; setprio(0); barrier.
// t=7 issues phantom tile-8 loads (k wraps to 0) for ledger uniformity.

#define STAGE_A(i)                                                             \
  {                                                                            \
    int r  = (i) * 32 + (tid >> 3);                                            \
    int sc = (tid & 7) ^ (r & 7);                                              \
    gload_lds16(Ag + (size_t)r * F_DIM + kbn + sc * 8,                         \
                sAn + (i) * 4096 + w * 1024);                                  \
  }

#define STAGE_B(j)                                                             \
  {                                                                            \
    int r  = (j) * 32 + (tid >> 3);                                            \
    int sc = (tid & 7) ^ (r & 7);                                              \
    gload_lds16(Bg + (size_t)r * F_DIM + kbn + sc * 8,                         \
                sBn + (j) * 4096 + w * 1024);                                  \
  }

__global__ __launch_bounds__(256, 3) void gemm_eps(
    const u16* __restrict__ A,   // [B_ROWS][F_DIM] bf16
    const u16* __restrict__ Bw,  // [K_PAD][F_DIM]  bf16 (padded rows are 0)
    const float* __restrict__ dsq,
    const float* __restrict__ wsq,
    const float* __restrict__ gamma,
    float* __restrict__ out) {
  __shared__ __align__(16) char lds[LDS_SZ];

  const int tid  = threadIdx.x;
  const int w    = tid >> 6;     // wave 0..3
  const int lane = tid & 63;
  const int lr   = lane & 15;
  const int lk4  = lane >> 4;
  const int wm   = w >> 1;       // 2 M-waves (64 rows each)
  const int wn   = w & 1;        // 2 N-waves (32 cols each)

  // XCD-aware swizzle (grid=2048, %8==0 -> bijective). 16 consecutive wg on
  // one XCD share the A-panel (same mt) -> A re-reads are local-L2 hits.
  const int bid = blockIdx.x;
  const int wg  = (bid & 7) * 256 + (bid >> 3);
  const int mt  = wg >> 4;       // 128 M-tiles
  const int nt  = wg & 15;       // 16 N-tiles
  const int m0  = mt * BM;
  const int n0  = nt * BN;

  const u16* Ag = A  + (size_t)m0 * F_DIM;
  const u16* Bg = Bw + (size_t)n0 * F_DIM;

  f32x4 acc[4][2];
#pragma unroll
  for (int i = 0; i < 4; ++i)
#pragma unroll
    for (int j = 0; j < 2; ++j) acc[i][j] = (f32x4){0.f, 0.f, 0.f, 0.f};

  // epilogue operands prefetched (latency hides under the K-loop)
  float g_[2], wq_[2];
  float4 dl[4];
#pragma unroll
  for (int ni = 0; ni < 2; ++ni) {
    int col = n0 + wn * 32 + ni * 16 + lr;
    g_[ni]  = (col < K_OUT) ? gamma[col] : 0.f;
    wq_[ni] = wsq[col & (K_PAD - 1)];
  }
#pragma unroll
  for (int mi = 0; mi < 4; ++mi)
    dl[mi] = *(const float4*)&dsq[m0 + wm * 64 + mi * 16 + lk4 * 4];

  // prologue: stage K-tile 0 into buf0 (6 loads/thread, left in flight)
  {
    char* sAn = lds + A0_OFF;
    char* sBn = lds + B0_OFF;
    const int kbn = 0;
    STAGE_A(0) STAGE_A(1) STAGE_A(2) STAGE_A(3)
    STAGE_B(0) STAGE_B(1)
  }

#pragma unroll 2
  for (int t = 0; t < 8; ++t) {
    const char* sAc = lds + ((t & 1) ? A1_OFF : A0_OFF);
    const char* sBc = lds + ((t & 1) ? B1_OFF : B0_OFF);
    char* sAn = lds + ((t & 1) ? A0_OFF : A1_OFF);
    char* sBn = lds + ((t & 1) ? B0_OFF : B1_OFF);
    const int kbn = ((t + 1) & 7) * BK;   // t=7 phantom wraps to k=0: harmless

    // issue next tile's 6 loads (in flight across this tile's compute)
    STAGE_A(0) STAGE_A(1) STAGE_A(2) STAGE_A(3)
    STAGE_B(0) STAGE_B(1)

    asm volatile("s_waitcnt vmcnt(6)" ::: "memory");  // tile t resident
    __builtin_amdgcn_s_barrier();
    asm volatile("" ::: "memory");

    short8 a[2][4], b[2][2];
#pragma unroll
    for (int kk = 0; kk < 2; ++kk) {
#pragma unroll
      for (int mi = 0; mi < 4; ++mi) {
        int rA = wm * 64 + mi * 16 + lr;
        a[kk][mi] = *(const short8*)(sAc + rA * 128 +
                                     ((((kk << 2) + lk4) ^ (rA & 7)) << 4));
      }
#pragma unroll
      for (int ni = 0; ni < 2; ++ni) {
        int rB = wn * 32 + ni * 16 + lr;
        b[kk][ni] = *(const short8*)(sBc + rB * 128 +
                                     ((((kk << 2) + lk4) ^ (rB & 7)) << 4));
      }
    }

    __builtin_amdgcn_s_setprio(1);
#pragma unroll
    for (int kk = 0; kk < 2; ++kk)
#pragma unroll
      for (int mi = 0; mi < 4; ++mi)
#pragma unroll
        for (int ni = 0; ni < 2; ++ni)
          acc[mi][ni] = __builtin_amdgcn_mfma_f32_16x16x32_bf16(
              a[kk][mi], b[kk][ni], acc[mi][ni], 0, 0, 0);
    __builtin_amdgcn_s_setprio(0);

    asm volatile("" ::: "memory");
    __builtin_amdgcn_s_barrier();   // buf reads done before t+1 overwrites
  }

  // ---- fused epilogue via LDS transpose (coalesced row stores) ----
  // First __syncthreads drains vmcnt(0)+lgkmcnt(0): phantom tile-8 stages land
  // before we overwrite LDS with the chunk buffer.
  float* ch = (float*)lds;       // chunk [64][68] f32 = 17.4KB (pad 68: 16B-
  const int rl = tid >> 2;       // aligned rows, small bank shift)
  const int cb = (tid & 3) << 2;
#pragma unroll
  for (int c = 0; c < 2; ++c) {
    __syncthreads();   // previous chunk fully read; K-loop LDS quiesced
    if (wm == c) {
#pragma unroll
      for (int mi = 0; mi < 4; ++mi) {
        const int row_l = mi * 16 + lk4 * 4;
#pragma unroll
        for (int j = 0; j < 4; ++j) {
          float dq = (j == 0) ? dl[mi].x : (j == 1) ? dl[mi].y
                   : (j == 2) ? dl[mi].z : dl[mi].w;
#pragma unroll
          for (int ni = 0; ni < 2; ++ni) {
            ch[(row_l + j) * 68 + wn * 32 + ni * 16 + lr] =
                g_[ni] * (2.f * acc[mi][ni][j] - dq - wq_[ni]);
          }
        }
      }
    }
    __syncthreads();   // chunk visible to all waves
#pragma unroll
    for (int s = 0; s < 4; ++s) {
      int col = cb + s * 16;
      if (n0 + col < K_OUT) {
        float4 v = *(const float4*)&ch[rl * 68 + col];
        *(float4*)&out[(size_t)(m0 + c * 64 + rl) * K_OUT + n0 + col] = v;
      }
    }
  }
}

extern "C" void kernel_launch(void* const* d_in, const int* in_sizes, int n_in,
                              void* d_out, int out_size, void* d_ws, size_t ws_size,
                              hipStream_t stream) {
  const float* D     = (const float*)d_in[0];
  const float* W     = (const float*)d_in[1];
  const float* gamma = (const float*)d_in[2];
  float* out = (float*)d_out;
  char*  ws  = (char*)d_ws;

  u16*   Db  = (u16*)(ws + OFF_DB);
  u16*   Wb  = (u16*)(ws + OFF_WB);
  float* dsq = (float*)(ws + OFF_DSQ);
  float* wsq = (float*)(ws + OFF_WSQ);

  prep<<<B_ROWS / 4 + K_PAD / 4, 256, 0, stream>>>(D, W, Db, Wb, dsq, wsq);

  // grid = (16384/128) * (1024/64) = 128*16 = 2048 blocks, 3 resident/CU
  gemm_eps<<<(B_ROWS / BM) * (K_PAD / BN), 256, 0, stream>>>(
      Db, Wb, dsq, wsq, gamma, out);
}